// Round 9
// baseline (2149.775 us; speedup 1.0000x reference)
//
#include <hip/hip_runtime.h>
#include <math.h>

// LSTM: B=128, T=256, D=256, H=1024, C=10
// Round 10: per-step path, optimized. Persistence CLOSED (R9 evidence:
//   coop launch fails under graph capture -> timed run was the fallback;
//   rocprof showed lstm_persist running at 5850us with VGPR=128 -> weights
//   remat'ed a 5th time and persist is 3x SLOWER than per-step even when it
//   runs).
//   Per-step theory of R1's 7.4us/step: 84 MB/step of B-fragment requests
//   (8 waves/block each redundantly streaming 40KB; 8 m-groups re-reading
//   the same weights), + 64-way staging-write bank conflict (R3 measured
//   1.47e8 SQ_LDS_BANK_CONFLICT on this staging code), + PF=4 B-prefetch
//   (~40cyc ahead vs ~200cyc L2 latency).
//   Fixes in lstm_step2 (same proven skeleton, epilogue, numerics as R1):
//   - Block = 32 rows x 16 cols x 4 gates; waves = 4 gates x 2 K-halves;
//     each wave computes BOTH 16-row tiles from ONE B stream:
//     zero duplicate B requests in a block -> 41 MB/step (was 84).
//   - Per-XCD weight footprint 8 n-tiles x 160KB = 1.3MB -> L2-resident
//     (natural id%8 = bx%8 grouping).
//   - Staging-dest XOR swizzle (slot ^= kt&7 into m bits; involution):
//     write phases conflict-free (was 64-way).
//   - B-prefetch depth 8 (arrays with const indices after full unroll --
//     R1-proven register pattern).
// Workspace layout (28,311,552 B total):
//   [0)          Wpack  bf16  10,485,760 B
//   [10485760)   xT     bf16  16,777,216 B   ([T][B][D], x transposed+cast)
//   [27262976)   h0     bf16     262,144 B
//   [27525120)   h1     bf16     262,144 B
//   [27787264)   c      fp32     524,288 B

#define BB 128
#define TT 256
#define DD 256
#define HH 1024
#define NKT 40   // 1280 / 32 k-tiles
#define KHT 20   // k-tiles per K-half wave
#define PFB 8    // B-fragment prefetch depth
#define PFA 4    // A-fragment prefetch depth

typedef __bf16 bf16x8 __attribute__((ext_vector_type(8)));
typedef float  f32x4  __attribute__((ext_vector_type(4)));
typedef unsigned short u16;
typedef u16 u16x8 __attribute__((ext_vector_type(8)));

__device__ __forceinline__ u16 f2bf(float f){
  unsigned u = __builtin_bit_cast(unsigned, f);
  u += 0x7fffu + ((u >> 16) & 1u);            // round-to-nearest-even
  return (u16)(u >> 16);
}
__device__ __forceinline__ float bf2f(u16 b){
  unsigned u = ((unsigned)b) << 16;
  return __builtin_bit_cast(float, u);
}
// A-tile slot bits: m=[0:3], q=[4:5], rh=[6], kt=[7:12]. XOR m-low3 with
// kt-low3: source bits (>=7) unchanged -> involution -> bijective. Makes the
// staging wave's 64 lanes (kt varies per 4 lanes) hit 8 distinct 16B bank
// groups -> conflict-free 8-phase ds_write_b128.
__device__ __forceinline__ int swz2(int slot){
  return slot ^ ((slot >> 7) & 7);
}

// ---- pack weights into MFMA B-fragment order -------------------------------
// Wpack[ct][kt][lane][j]: ct in [0,256) covers gate-cols [ct*16, ct*16+16)
// (col = gate*1024 + n); element = W[k = kt*32 + (lane>>4)*8 + j][col = ct*16 + (lane&15)]
__global__ void prep_wpack(const float* __restrict__ Wfx, const float* __restrict__ Wix,
                           const float* __restrict__ Wgx, const float* __restrict__ Wox,
                           const float* __restrict__ Wfh, const float* __restrict__ Wih,
                           const float* __restrict__ Wgh, const float* __restrict__ Woh,
                           u16* __restrict__ Wpack){
  int id = blockIdx.x * 256 + threadIdx.x;    // [0, 655360)
  int lane = id & 63;
  int kt = (id >> 6) % NKT;
  int ct = id / (64 * NKT);
  int col = ct * 16 + (lane & 15);
  int g = col >> 10, n = col & 1023;
  int kbase = kt * 32 + (lane >> 4) * 8;
  const float* Wx = (g==0) ? Wfx : (g==1) ? Wix : (g==2) ? Wgx : Wox;
  const float* Wh = (g==0) ? Wfh : (g==1) ? Wih : (g==2) ? Wgh : Woh;
  u16x8 v;
  #pragma unroll
  for (int j = 0; j < 8; ++j){
    int k = kbase + j;
    float f = (k < DD) ? Wx[k * HH + n] : Wh[(k - DD) * HH + n];
    v[j] = f2bf(f);
  }
  *(u16x8*)(Wpack + (size_t)id * 8) = v;      // dst index == id (by construction)
}

// ---- transpose+cast x: xT[t][b][d] = bf16(x[b][t][d]) ----------------------
__global__ void prep_xT(const float* __restrict__ x, u16* __restrict__ xT){
  int id = blockIdx.x * 256 + threadIdx.x;    // [0, 1048576), 8 elems each
  int t = id >> 12;
  int b = (id >> 5) & 127;
  int d0 = (id & 31) * 8;
  const float* src = x + ((size_t)b * TT + t) * DD + d0;
  u16x8 v;
  #pragma unroll
  for (int j = 0; j < 8; ++j) v[j] = f2bf(src[j]);
  *(u16x8*)(xT + (size_t)id * 8) = v;
}

// ---- one LSTM time step: GEMM (bf16 MFMA) + gate activations + state update
// Block: 32 batch rows x 16 hidden cols x 4 gates. Waves: g = w&3, kh = w>>2.
// Each wave: one B stream (20 k-tiles), BOTH 16-row A tiles -> 40 MFMAs.
__global__ __launch_bounds__(512) void lstm_step2(
    const u16* __restrict__ xTt,   // [128][256] bf16 (t-slice of xT)
    const u16* __restrict__ Wpack,
    const u16* __restrict__ hin,   // [128][1024] bf16
    u16* __restrict__ hout,        // [128][1024] bf16
    float* __restrict__ cbuf,      // [128][1024] fp32
    const float* __restrict__ bfv, const float* __restrict__ biv,
    const float* __restrict__ bgv, const float* __restrict__ bov){
  __shared__ u16x8 As4[NKT * 128]; // 80 KB: A tile (32 rows), swizzled
  __shared__ float pLds[32][68];   // K-half partial exchange (8.7 KB)
  __shared__ float gLds[32][68];   // gate exchange (8.7 KB)
  const int tid = threadIdx.x;
  const int bx = blockIdx.x;       // n-tile [0,64); bx%8 = XCD (L2 grouping)
  const int n0 = bx * 16;
  const int m0 = blockIdx.y * 32;  // batch-row group [0,4)

  const int w = tid >> 6, lane = tid & 63, cr = lane & 15, q4 = lane >> 4;
  const int g  = w & 3;            // gate
  const int kh = w >> 2;           // K-half
  const int ktBeg = kh * KHT;

  // B stream for (gate g, cols n0..n0+15): ct = g*64 + bx. Issue prologue
  // loads BEFORE staging so L2 latency hides under the staging phase.
  const u16x8* wq = (const u16x8*)Wpack + (size_t)(g * 64 + bx) * NKT * 64 + lane;
  u16x8 bP[PFB];
  #pragma unroll
  for (int i = 0; i < PFB; ++i) bP[i] = wq[(size_t)(ktBeg + i) * 64];

  // Stage A = [x_t | h] for rows m0..m0+32 in MFMA A-fragment order, swizzled.
  // chunk ch -> row mr = ch/160, k0 = (ch%160)*8.
  #pragma unroll
  for (int it = 0; it < 10; ++it){
    int ch = tid + it * 512;
    int mr = ch / 160;
    int k0 = (ch - mr * 160) * 8;
    const u16* src = (k0 < DD) ? (xTt + (m0 + mr) * DD + k0)
                               : (hin + (m0 + mr) * HH + (k0 - DD));
    u16x8 val = *(const u16x8*)src;
    int slot = (k0 >> 5) * 128 + (mr >> 4) * 64 + ((k0 >> 3) & 3) * 16 + (mr & 15);
    As4[swz2(slot)] = val;
  }
  __syncthreads();

  u16x8 aA[PFA], aB[PFA];
  #pragma unroll
  for (int i = 0; i < PFA; ++i){
    aA[i] = As4[swz2((ktBeg + i) * 128 + lane)];        // rows 0..15
    aB[i] = As4[swz2((ktBeg + i) * 128 + 64 + lane)];   // rows 16..31
  }

  f32x4 accA = {0.f, 0.f, 0.f, 0.f}, accB = {0.f, 0.f, 0.f, 0.f};
  #pragma unroll
  for (int i = 0; i < KHT; ++i){
    u16x8 b  = bP[i & (PFB - 1)];
    u16x8 a0 = aA[i & (PFA - 1)];
    u16x8 a1 = aB[i & (PFA - 1)];
    if (i + PFB < KHT)
      bP[i & (PFB - 1)] = wq[(size_t)(ktBeg + i + PFB) * 64];
    if (i + PFA < KHT){
      aA[i & (PFA - 1)] = As4[swz2((ktBeg + i + PFA) * 128 + lane)];
      aB[i & (PFA - 1)] = As4[swz2((ktBeg + i + PFA) * 128 + 64 + lane)];
    }
    accA = __builtin_amdgcn_mfma_f32_16x16x32_bf16(__builtin_bit_cast(bf16x8, a0),
             __builtin_bit_cast(bf16x8, b), accA, 0, 0, 0);
    accB = __builtin_amdgcn_mfma_f32_16x16x32_bf16(__builtin_bit_cast(bf16x8, a1),
             __builtin_bit_cast(bf16x8, b), accB, 0, 0, 0);
  }

  // combine K-halves (C/D layout: col=lane&15, local row=q4*4+r; accB rows +16)
  if (kh){
    #pragma unroll
    for (int r = 0; r < 4; ++r){
      pLds[q4 * 4 + r][g * 16 + cr]      = accA[r];
      pLds[16 + q4 * 4 + r][g * 16 + cr] = accB[r];
    }
  }
  __syncthreads();
  if (!kh){
    const float* bptr = (g==0) ? bfv : (g==1) ? biv : (g==2) ? bgv : bov;
    const float bias = bptr[n0 + cr];
    #pragma unroll
    for (int r = 0; r < 4; ++r){
      gLds[q4 * 4 + r][g * 16 + cr] =
          accA[r] + pLds[q4 * 4 + r][g * 16 + cr] + bias;
      gLds[16 + q4 * 4 + r][g * 16 + cr] =
          accB[r] + pLds[16 + q4 * 4 + r][g * 16 + cr] + bias;
    }
  }
  __syncthreads();

  // fused LSTM cell update: 32 rows x 16 cols = 512 units, 1 per thread
  {
    int crow = tid >> 4, cnn = tid & 15;
    float fp = gLds[crow][cnn],      ip = gLds[crow][16 + cnn];
    float gp = gLds[crow][32 + cnn], op = gLds[crow][48 + cnn];
    float fs = 1.f / (1.f + expf(-fp));
    float is = 1.f / (1.f + expf(-ip));
    float gs = tanhf(gp);
    float os = 1.f / (1.f + expf(-op));
    int gi = (m0 + crow) * HH + n0 + cnn;
    float cn = gs * is + cbuf[gi] * fs;
    cbuf[gi] = cn;
    hout[gi] = f2bf(tanhf(cn) * os);
  }
}

// ---- out[b][c] = h_T[b] . Wph[:,c] + bp[c] ---------------------------------
__global__ void final_proj(const u16* __restrict__ h, const float* __restrict__ Wph,
                           const float* __restrict__ bp, float* __restrict__ out){
  __shared__ float red[10][256];
  int b = blockIdx.x, tid = threadIdx.x;
  float p[10];
  #pragma unroll
  for (int c = 0; c < 10; ++c) p[c] = 0.f;
  for (int k = tid; k < HH; k += 256){
    float hv = bf2f(h[b * HH + k]);
    const float* wr = Wph + (size_t)k * 10;
    #pragma unroll
    for (int c = 0; c < 10; ++c) p[c] += hv * wr[c];
  }
  #pragma unroll
  for (int c = 0; c < 10; ++c) red[c][tid] = p[c];
  __syncthreads();
  for (int s = 128; s > 0; s >>= 1){
    if (tid < s){
      #pragma unroll
      for (int c = 0; c < 10; ++c) red[c][tid] += red[c][tid + s];
    }
    __syncthreads();
  }
  if (tid < 10) out[b * 10 + tid] = red[tid][0] + bp[tid];
}

extern "C" void kernel_launch(void* const* d_in, const int* in_sizes, int n_in,
                              void* d_out, int out_size, void* d_ws, size_t ws_size,
                              hipStream_t stream){
  (void)in_sizes; (void)n_in; (void)out_size; (void)ws_size;
  const float* x   = (const float*)d_in[0];
  const float* Wfx = (const float*)d_in[1];
  const float* Wix = (const float*)d_in[2];
  const float* Wgx = (const float*)d_in[3];
  const float* Wox = (const float*)d_in[4];
  const float* Wfh = (const float*)d_in[5];
  const float* Wih = (const float*)d_in[6];
  const float* Wgh = (const float*)d_in[7];
  const float* Woh = (const float*)d_in[8];
  const float* bfv = (const float*)d_in[9];
  const float* biv = (const float*)d_in[10];
  const float* bgv = (const float*)d_in[11];
  const float* bov = (const float*)d_in[12];
  const float* Wph = (const float*)d_in[13];
  const float* bp  = (const float*)d_in[14];

  char* ws = (char*)d_ws;
  u16*  Wpack = (u16*)ws;                    // 10,485,760 B
  u16*  xT    = (u16*)(ws + 10485760);       // 16,777,216 B
  u16*  h0    = (u16*)(ws + 27262976);       //    262,144 B
  u16*  h1    = (u16*)(ws + 27525120);       //    262,144 B
  float* cb   = (float*)(ws + 27787264);     //    524,288 B

  prep_wpack<<<2560, 256, 0, stream>>>(Wfx, Wix, Wgx, Wox, Wfh, Wih, Wgh, Woh, Wpack);
  prep_xT<<<4096, 256, 0, stream>>>(x, xT);
  hipMemsetAsync(h0, 0, 262144, stream);
  hipMemsetAsync(cb, 0, 524288, stream);

  for (int t = 0; t < TT; ++t){
    const u16* hin  = (t & 1) ? h1 : h0;
    u16*       hout = (t & 1) ? h0 : h1;
    lstm_step2<<<dim3(64, 4), 512, 0, stream>>>(xT + (size_t)t * BB * DD, Wpack,
                                                hin, hout, cb, bfv, biv, bgv, bov);
  }
  // t=255 (odd) wrote h0 -> final hidden state lives in h0
  final_proj<<<128, 256, 0, stream>>>(h0, Wph, bp, (float*)d_out);
}

// Round 10
// 1950.900 us; speedup vs baseline: 1.1019x; 1.1019x over previous
//
#include <hip/hip_runtime.h>
#include <math.h>

// LSTM: B=128, T=256, D=256, H=1024, C=10
// Round 11: R1 skeleton (proven 1983us) + three evidence-backed fixes.
//   R10 post-mortem: the 32-row B-dedup restructure traded 43MB/step L2 for
//   a doubled LDS stream + doubled staging -> +1us/step net. Same-stream
//   kernels serialize fully, so there was no cross-step overlap to lose.
//   Reverted. Persistence remains CLOSED (R9: coop+capture fails; persist
//   3x slower even when running, weights remat 5x attempts).
//   Fixes on the R1 kernel:
//   1) Staging-write bank conflict (R3 measured 1.47e8 SQ_LDS_BANK_CONFLICT
//      = ~0.9us/step): involution swizzle slot ^= ((slot>>6)&7) ^
//      (((slot>>4)&3)<<1). 8 consecutive staging lanes (q per lane, kt per
//      4 lanes) -> 8 distinct bank groups; R4's variant left 2-way (6.3e7),
//      this removes the lane-parity collision. K-loop reads stay spread.
//   2) __expf-based sigmoid/tanh (R3/R4-proven: absmax identical 3.05e-5).
//   3) c-state prefetch at kernel entry (hides ~500cyc global latency that
//      sat exposed in the epilogue) + B-prefetch depth 4->5 (~200cyc L2).
// Workspace layout (28,311,552 B total):
//   [0)          Wpack  bf16  10,485,760 B
//   [10485760)   xT     bf16  16,777,216 B   ([T][B][D], x transposed+cast)
//   [27262976)   h0     bf16     262,144 B
//   [27525120)   h1     bf16     262,144 B
//   [27787264)   c      fp32     524,288 B

#define BB 128
#define TT 256
#define DD 256
#define HH 1024
#define NKT 40   // 1280 / 32 k-tiles
#define KHT 20   // k-tiles per K-half wave
#define PFA 4    // A-fragment prefetch depth
#define PFB 5    // B-fragment prefetch depth

typedef __bf16 bf16x8 __attribute__((ext_vector_type(8)));
typedef float  f32x4  __attribute__((ext_vector_type(4)));
typedef unsigned short u16;
typedef u16 u16x8 __attribute__((ext_vector_type(8)));

__device__ __forceinline__ u16 f2bf(float f){
  unsigned u = __builtin_bit_cast(unsigned, f);
  u += 0x7fffu + ((u >> 16) & 1u);            // round-to-nearest-even
  return (u16)(u >> 16);
}
__device__ __forceinline__ float bf2f(u16 b){
  unsigned u = ((unsigned)b) << 16;
  return __builtin_bit_cast(float, u);
}
__device__ __forceinline__ float sigm(float x){
  return 1.f / (1.f + __expf(-x));            // R3/R4-proven numerics
}
__device__ __forceinline__ float tanh_fast(float x){
  return 2.f / (1.f + __expf(-2.f * x)) - 1.f;
}
// As4 slot bits: m=[0:3], q=[4:5], kt=[6:11]. XOR kt-low3 and q into m-low3.
// Source bits (>=4) unchanged -> involution -> bijective. Staging wave:
// q increments per lane, kt per 4 lanes -> 8 consecutive lanes hit 8
// distinct bank groups (R4's variant collided lanes of equal q-parity).
__device__ __forceinline__ int swzb(int slot){
  return slot ^ ((slot >> 6) & 7) ^ (((slot >> 4) & 3) << 1);
}

// ---- pack weights into MFMA B-fragment order -------------------------------
// Wpack[ct][kt][lane][j]: ct in [0,256) covers gate-cols [ct*16, ct*16+16)
// (col = gate*1024 + n); element = W[k = kt*32 + (lane>>4)*8 + j][col = ct*16 + (lane&15)]
__global__ void prep_wpack(const float* __restrict__ Wfx, const float* __restrict__ Wix,
                           const float* __restrict__ Wgx, const float* __restrict__ Wox,
                           const float* __restrict__ Wfh, const float* __restrict__ Wih,
                           const float* __restrict__ Wgh, const float* __restrict__ Woh,
                           u16* __restrict__ Wpack){
  int id = blockIdx.x * 256 + threadIdx.x;    // [0, 655360)
  int lane = id & 63;
  int kt = (id >> 6) % NKT;
  int ct = id / (64 * NKT);
  int col = ct * 16 + (lane & 15);
  int g = col >> 10, n = col & 1023;
  int kbase = kt * 32 + (lane >> 4) * 8;
  const float* Wx = (g==0) ? Wfx : (g==1) ? Wix : (g==2) ? Wgx : Wox;
  const float* Wh = (g==0) ? Wfh : (g==1) ? Wih : (g==2) ? Wgh : Woh;
  u16x8 v;
  #pragma unroll
  for (int j = 0; j < 8; ++j){
    int k = kbase + j;
    float f = (k < DD) ? Wx[k * HH + n] : Wh[(k - DD) * HH + n];
    v[j] = f2bf(f);
  }
  *(u16x8*)(Wpack + (size_t)id * 8) = v;      // dst index == id (by construction)
}

// ---- transpose+cast x: xT[t][b][d] = bf16(x[b][t][d]) ----------------------
__global__ void prep_xT(const float* __restrict__ x, u16* __restrict__ xT){
  int id = blockIdx.x * 256 + threadIdx.x;    // [0, 1048576), 8 elems each
  int t = id >> 12;
  int b = (id >> 5) & 127;
  int d0 = (id & 31) * 8;
  const float* src = x + ((size_t)b * TT + t) * DD + d0;
  u16x8 v;
  #pragma unroll
  for (int j = 0; j < 8; ++j) v[j] = f2bf(src[j]);
  *(u16x8*)(xT + (size_t)id * 8) = v;
}

// ---- one LSTM time step: GEMM (bf16 MFMA) + gate activations + state update
__global__ __launch_bounds__(512) void lstm_step(
    const u16* __restrict__ xTt,   // [128][256] bf16 (t-slice of xT)
    const u16* __restrict__ Wpack,
    const u16* __restrict__ hin,   // [128][1024] bf16
    u16* __restrict__ hout,        // [128][1024] bf16
    float* __restrict__ cbuf,      // [128][1024] fp32
    const float* __restrict__ bfv, const float* __restrict__ biv,
    const float* __restrict__ bgv, const float* __restrict__ bov){
  __shared__ u16x8 As4[NKT * 64];  // 40 KB: A tile in fragment order (swizzled)
  __shared__ float gLds[16][132];  // gate exchange (8.25 KB)
  __shared__ float pLds[16][132];  // K-half partial-sum exchange (8.25 KB)
  const int tid = threadIdx.x;
  const int n0 = blockIdx.x * 32;  // hidden-unit tile
  const int m0 = blockIdx.y * 16;  // batch-row tile

  // cell-update ownership fixed by tid -> prefetch c-state NOW (hides ~500cyc)
  const int crow = tid >> 5, cnn = tid & 31;
  const int gi = (m0 + crow) * HH + n0 + cnn;
  const float cprev = cbuf[gi];

  const int w = tid >> 6, lane = tid & 63, cr = lane & 15, q4 = lane >> 4;
  const int g  = w & 3;            // gate
  const int kh = w >> 2;           // K-half: kt in [kh*20, kh*20+20)
  const int ktBeg = kh * KHT;

  // B fragment pointers (global, L2-resident pack); prologue loads issued
  // BEFORE staging so weight latency overlaps the A-staging phase.
  const size_t ct0 = (size_t)(g * 64 + blockIdx.x * 2);  // 2 col-tiles of gate g
  const u16x8* Wp = (const u16x8*)Wpack;
  const u16x8* wq0 = Wp + ct0 * NKT * 64 + lane;
  const u16x8* wq1 = wq0 + NKT * 64;

  u16x8 aP[PFA], b0P[PFB], b1P[PFB];
  #pragma unroll
  for (int i = 0; i < PFB; ++i){
    b0P[i] = wq0[(size_t)(ktBeg + i) * 64];
    b1P[i] = wq1[(size_t)(ktBeg + i) * 64];
  }

  // Stage A = [x_t rows | h rows] into LDS in MFMA A-fragment order, swizzled.
  // chunk ch -> row m = ch/160, k0 = (ch%160)*8 ; slot = kt*64 + 16*q + m
  #pragma unroll
  for (int it = 0; it < 10; ++it){
    int ch = tid + it * 256;       // 512 thr x 5? no: 10 iters x 512 = wrong
    ch = tid + it * 512;           // (kept explicit: 10 x 512 = 5120 hmm)
    if (it >= 5) break;            // exactly 5 iterations of 512 threads
    int m = ch / 160;
    int k0 = (ch - m * 160) * 8;
    const u16* src = (k0 < DD) ? (xTt + (m0 + m) * DD + k0)
                               : (hin + (m0 + m) * HH + (k0 - DD));
    u16x8 val = *(const u16x8*)src;
    int kt = k0 >> 5, q = (k0 >> 3) & 3;
    As4[swzb(kt * 64 + 16 * q + m)] = val;
  }
  __syncthreads();

  #pragma unroll
  for (int i = 0; i < PFA; ++i) aP[i] = As4[swzb((ktBeg + i) * 64 + lane)];

  f32x4 acc0 = {0.f, 0.f, 0.f, 0.f}, acc1 = {0.f, 0.f, 0.f, 0.f};
  #pragma unroll
  for (int kt = 0; kt < KHT; ++kt){
    u16x8 ac = aP[kt % PFA], b0 = b0P[kt % PFB], b1 = b1P[kt % PFB];
    if (kt + PFA < KHT)
      aP[kt % PFA] = As4[swzb((ktBeg + kt + PFA) * 64 + lane)];
    if (kt + PFB < KHT){
      b0P[kt % PFB] = wq0[(size_t)(ktBeg + kt + PFB) * 64];
      b1P[kt % PFB] = wq1[(size_t)(ktBeg + kt + PFB) * 64];
    }
    acc0 = __builtin_amdgcn_mfma_f32_16x16x32_bf16(__builtin_bit_cast(bf16x8, ac),
             __builtin_bit_cast(bf16x8, b0), acc0, 0, 0, 0);
    acc1 = __builtin_amdgcn_mfma_f32_16x16x32_bf16(__builtin_bit_cast(bf16x8, ac),
             __builtin_bit_cast(bf16x8, b1), acc1, 0, 0, 0);
  }

  // combine K-halves (C/D layout: col=lane&15, row=q4*4+r)
  if (kh){
    #pragma unroll
    for (int r = 0; r < 4; ++r){
      pLds[q4 * 4 + r][g * 32 + cr]      = acc0[r];
      pLds[q4 * 4 + r][g * 32 + 16 + cr] = acc1[r];
    }
  }
  __syncthreads();
  if (!kh){
    const float* bptr = (g==0) ? bfv : (g==1) ? biv : (g==2) ? bgv : bov;
    float bias0 = bptr[n0 + cr], bias1 = bptr[n0 + 16 + cr];
    #pragma unroll
    for (int r = 0; r < 4; ++r){
      gLds[q4 * 4 + r][g * 32 + cr] =
          acc0[r] + pLds[q4 * 4 + r][g * 32 + cr] + bias0;
      gLds[q4 * 4 + r][g * 32 + 16 + cr] =
          acc1[r] + pLds[q4 * 4 + r][g * 32 + 16 + cr] + bias1;
    }
  }
  __syncthreads();

  // fused LSTM cell update: 512 (row, hidden) units, 1 per thread
  {
    float fp = gLds[crow][cnn],      ip = gLds[crow][32 + cnn];
    float gp = gLds[crow][64 + cnn], op = gLds[crow][96 + cnn];
    float fs = sigm(fp);
    float is = sigm(ip);
    float gs = tanh_fast(gp);
    float os = sigm(op);
    float cn = gs * is + cprev * fs;
    cbuf[gi] = cn;
    hout[gi] = f2bf(tanh_fast(cn) * os);
  }
}

// ---- out[b][c] = h_T[b] . Wph[:,c] + bp[c] ---------------------------------
__global__ void final_proj(const u16* __restrict__ h, const float* __restrict__ Wph,
                           const float* __restrict__ bp, float* __restrict__ out){
  __shared__ float red[10][256];
  int b = blockIdx.x, tid = threadIdx.x;
  float p[10];
  #pragma unroll
  for (int c = 0; c < 10; ++c) p[c] = 0.f;
  for (int k = tid; k < HH; k += 256){
    float hv = bf2f(h[b * HH + k]);
    const float* wr = Wph + (size_t)k * 10;
    #pragma unroll
    for (int c = 0; c < 10; ++c) p[c] += hv * wr[c];
  }
  #pragma unroll
  for (int c = 0; c < 10; ++c) red[c][tid] = p[c];
  __syncthreads();
  for (int s = 128; s > 0; s >>= 1){
    if (tid < s){
      #pragma unroll
      for (int c = 0; c < 10; ++c) red[c][tid] += red[c][tid + s];
    }
    __syncthreads();
  }
  if (tid < 10) out[b * 10 + tid] = red[tid][0] + bp[tid];
}

extern "C" void kernel_launch(void* const* d_in, const int* in_sizes, int n_in,
                              void* d_out, int out_size, void* d_ws, size_t ws_size,
                              hipStream_t stream){
  (void)in_sizes; (void)n_in; (void)out_size; (void)ws_size;
  const float* x   = (const float*)d_in[0];
  const float* Wfx = (const float*)d_in[1];
  const float* Wix = (const float*)d_in[2];
  const float* Wgx = (const float*)d_in[3];
  const float* Wox = (const float*)d_in[4];
  const float* Wfh = (const float*)d_in[5];
  const float* Wih = (const float*)d_in[6];
  const float* Wgh = (const float*)d_in[7];
  const float* Woh = (const float*)d_in[8];
  const float* bfv = (const float*)d_in[9];
  const float* biv = (const float*)d_in[10];
  const float* bgv = (const float*)d_in[11];
  const float* bov = (const float*)d_in[12];
  const float* Wph = (const float*)d_in[13];
  const float* bp  = (const float*)d_in[14];

  char* ws = (char*)d_ws;
  u16*  Wpack = (u16*)ws;                    // 10,485,760 B
  u16*  xT    = (u16*)(ws + 10485760);       // 16,777,216 B
  u16*  h0    = (u16*)(ws + 27262976);       //    262,144 B
  u16*  h1    = (u16*)(ws + 27525120);       //    262,144 B
  float* cb   = (float*)(ws + 27787264);     //    524,288 B

  prep_wpack<<<2560, 256, 0, stream>>>(Wfx, Wix, Wgx, Wox, Wfh, Wih, Wgh, Woh, Wpack);
  prep_xT<<<4096, 256, 0, stream>>>(x, xT);
  hipMemsetAsync(h0, 0, 262144, stream);
  hipMemsetAsync(cb, 0, 524288, stream);

  for (int t = 0; t < TT; ++t){
    const u16* hin  = (t & 1) ? h1 : h0;
    u16*       hout = (t & 1) ? h0 : h1;
    lstm_step<<<dim3(32, 8), 512, 0, stream>>>(xT + (size_t)t * BB * DD, Wpack,
                                               hin, hout, cb, bfv, biv, bgv, bov);
  }
  // t=255 (odd) wrote h0 -> final hidden state lives in h0
  final_proj<<<128, 256, 0, stream>>>(h0, Wph, bp, (float*)d_out);
}